// Round 9
// baseline (38.481 us; speedup 1.0000x reference)
//
#include <hip/hip_runtime.h>
#include <math.h>

// Fused plan+sample for TemporalSamplingUpSampler.
// R2 instruction mix (NT float4 stores + plain global gathers + distributed
// double-precision plan), reshaped tiles to lengthen DRAM write runs:
// block = 1024 t-cols x 128 channels; grid = (T/1024) x 2 = 256 blocks
// (1/CU, plan paid once per CU). Per channel a wave issues 4 back-to-back
// NT stores = 4KB contiguous (vs 1KB in R2) before jumping rows.
// out[0, c, t] = A[c, seg(t)] * w(t); C=256, K=256, T=131072.
//
// Plan (distributed over 256 threads, mirrors reference bit-exactly):
//   Lp = f32( T * exp(L-max) / sum )  in double (jax f32 softmax proxy)
//   r  = max(rint(Lp),0); total = sum r; l_max = int(max(Lp)+0.5)
//   j(t) = min(floor(t * (total/T)), total-1)  in double (numpy)
//   seg = bsearch(cum, j); loc = j - cum[seg]
//   x = (2*loc+1)/l_max - 1; xs = s*x + tt; p = ((xs+1)*100-1)/2
//   w = (1-frac)*[p0 in 0..99] + frac*[p0 in -1..98]

#define KMAX 256
#define TCOLS 1024            // t-columns per block
#define QTRS  4               // 4 x 256-column quarters

typedef float f32x4 __attribute__((ext_vector_type(4)));
typedef int   i32x4 __attribute__((ext_vector_type(4)));

__global__ __launch_bounds__(256) void fused_kernel(const float* __restrict__ A,
                                                    const float* __restrict__ L,
                                                    float* __restrict__ out,
                                                    int K, int C, int T, int Cl) {
    __shared__ float  s_s[KMAX];
    __shared__ float  s_t[KMAX];
    __shared__ int    s_cum[KMAX + 1];
    __shared__ int    s_seg[TCOLS];
    __shared__ float  s_w[TCOLS];
    __shared__ double sd[4];
    __shared__ float  sf[4];
    __shared__ int    si[4];

    const int tid  = threadIdx.x;
    const int lane = tid & 63;
    const int wid  = tid >> 6;

    const float Lv = (tid < K) ? L[tid] : -INFINITY;

    // ---- max(L): wave shfl-reduce, then 4 wave partials ----
    float m = Lv;
    #pragma unroll
    for (int o = 32; o > 0; o >>= 1) m = fmaxf(m, __shfl_xor(m, o));
    if (lane == 0) sf[wid] = m;
    __syncthreads();
    const float maxL = fmaxf(fmaxf(sf[0], sf[1]), fmaxf(sf[2], sf[3]));

    // ---- sum(exp(L-max)) in double ----
    const double e = (tid < K) ? exp((double)Lv - (double)maxL) : 0.0;
    double se = e;
    #pragma unroll
    for (int o = 32; o > 0; o >>= 1) se += __shfl_xor(se, o);
    if (lane == 0) sd[wid] = se;
    __syncthreads();
    const double S = sd[0] + sd[1] + sd[2] + sd[3];

    // Lp as f32 (mirrors jax f32 softmax result)
    const float Lp = (tid < K) ? (float)((double)T * e / S) : 0.0f;

    // ---- l_max = int(max(Lp) + 0.5) ----
    float mp = (tid < K) ? Lp : 0.0f;
    #pragma unroll
    for (int o = 32; o > 0; o >>= 1) mp = fmaxf(mp, __shfl_xor(mp, o));
    __syncthreads();              // everyone done reading phase-1 sf
    if (lane == 0) sf[wid] = mp;
    __syncthreads();
    const int l_max = (int)((double)fmaxf(fmaxf(sf[0], sf[1]), fmaxf(sf[2], sf[3])) + 0.5);

    // ---- r = max(rint(Lp),0); inclusive scan -> cum ----
    int r = 0;
    if (tid < K) {
        r = (int)rintf(Lp);
        if (r < 0) r = 0;
    }
    int v = r;
    #pragma unroll
    for (int o = 1; o < 64; o <<= 1) {
        const int n = __shfl_up(v, o);
        if (lane >= o) v += n;
    }
    if (lane == 63) si[wid] = v;
    __syncthreads();
    int offset = 0;
    for (int w = 0; w < wid; ++w) offset += si[w];
    const int total = si[0] + si[1] + si[2] + si[3];
    if (tid == 0) s_cum[0] = 0;
    if (tid < K) {
        s_cum[tid + 1] = v + offset;
        const float fl = (float)l_max;
        s_s[tid] = fl / Lp;
        s_t[tid] = (fl - Lp) / Lp;
    }
    __syncthreads();

    // ---- per-thread: 4 consecutive columns' (seg, w) ----
    const int t0 = blockIdx.x * TCOLS;
    {
        const double ratio = (double)total / (double)T;
        #pragma unroll
        for (int u = 0; u < 4; ++u) {
            const int lc = tid * 4 + u;
            const int t  = t0 + lc;
            int   seg = 0;
            float w   = 0.0f;
            if (t < T) {
                int j = (int)floor((double)t * ratio);
                if (j > total - 1) j = total - 1;
                if (j < 0) j = 0;

                int lo = 0, hi = K - 1;
                while (lo < hi) {
                    const int mid = (lo + hi) >> 1;
                    if (s_cum[mid + 1] > j) hi = mid; else lo = mid + 1;
                }
                seg = lo;
                const int loc = j - s_cum[seg];

                const float x  = (2.0f * (float)loc + 1.0f) / (float)l_max - 1.0f;
                const float xs = s_s[seg] * x + s_t[seg];
                const float p  = ((xs + 1.0f) * 100.0f - 1.0f) * 0.5f;
                const float p0 = floorf(p);
                const float w1 = p - p0;
                if (p0 >= 0.0f && p0 <= 99.0f)  w += 1.0f - w1;
                if (p0 >= -1.0f && p0 <= 98.0f) w += w1;
            }
            s_seg[lc] = seg;
            s_w[lc]   = w;
        }
    }
    __syncthreads();

    // ---- preload this lane's seg/w for all 4 quarters into registers ----
    i32x4 sg[QTRS];
    f32x4 wt[QTRS];
    #pragma unroll
    for (int q = 0; q < QTRS; ++q) {
        sg[q] = *(const i32x4*)&s_seg[q * 256 + lane * 4];
        wt[q] = *(const f32x4*)&s_w  [q * 256 + lane * 4];
    }

    // ---- stream: wave wid owns channels c0+wid, +4, ... ; per channel,
    //      4 back-to-back NT stores = 4KB contiguous ----
    const int c0 = blockIdx.y * Cl;

    if (t0 + TCOLS <= T) {
        for (int cl = wid; cl < Cl; cl += 4) {
            const int c = c0 + cl;
            const float* __restrict__ Ar = A + (size_t)c * K;
            float* __restrict__ orow = out + (size_t)c * T + t0;
            #pragma unroll
            for (int q = 0; q < QTRS; ++q) {
                f32x4 vv;
                vv.x = Ar[sg[q].x] * wt[q].x;
                vv.y = Ar[sg[q].y] * wt[q].y;
                vv.z = Ar[sg[q].z] * wt[q].z;
                vv.w = Ar[sg[q].w] * wt[q].w;
                __builtin_nontemporal_store(vv, (f32x4*)(orow + q * 256 + lane * 4));
            }
        }
    } else {
        for (int cl = wid; cl < Cl; cl += 4) {
            const int c = c0 + cl;
            const float* __restrict__ Ar = A + (size_t)c * K;
            for (int q = 0; q < QTRS; ++q) {
                const int tq = t0 + q * 256 + lane * 4;
                const int sgq[4] = {sg[q].x, sg[q].y, sg[q].z, sg[q].w};
                const float wtq[4] = {wt[q].x, wt[q].y, wt[q].z, wt[q].w};
                for (int u = 0; u < 4; ++u) {
                    const int t = tq + u;
                    if (t < T) out[(size_t)c * T + t] = Ar[sgq[u]] * wtq[u];
                }
            }
        }
    }
}

extern "C" void kernel_launch(void* const* d_in, const int* in_sizes, int n_in,
                              void* d_out, int out_size, void* d_ws, size_t ws_size,
                              hipStream_t stream) {
    const float* A = (const float*)d_in[0];
    const float* L = (const float*)d_in[1];

    const int K = in_sizes[1];                 // 256
    const int C = in_sizes[0] / K;             // 256
    const int T = out_size / C;                // 131072

    const int csplit = (C % 8 == 0) ? 2 : 1;
    const int Cl = C / csplit;

    const int nblkx = (T + TCOLS - 1) / TCOLS; // 128
    dim3 grid(nblkx, csplit);                  // 256 blocks -> 1 per CU
    fused_kernel<<<grid, 256, 0, stream>>>(A, L, (float*)d_out, K, C, T, Cl);
}

// Round 10
// 31.097 us; speedup vs baseline: 1.2374x; 1.2374x over previous
//
#include <hip/hip_runtime.h>
#include <math.h>

// Fused plan+sample for TemporalSamplingUpSampler — FINAL (R2 configuration,
// best measured: 31.1us across 8 rounds of A/B; all 7 perturbations regressed:
//   R3 wave-redundant plan  34.9 | R4 1-barrier plan      34.9
//   R5 uniform-seg fastpath 39.3 | R6 plain (non-NT) stores 34.8
//   R7 LDS-staged gathers   33.3 | R8 1024-thr blocks     35.0
//   R9 4KB-run tiling       38.5
// NT stores confirmed +3.7us; plain global gathers confirmed best).
// out[0, c, t] = A[c, seg(t)] * w(t); C=256, K=256, T=131072 (from in_sizes).
//
// Plan (distributed across 256 threads, double precision, mirrors reference):
//   Lp = f32( T * exp(L-max) / sum );  r = max(rint(Lp),0); total = sum r
//   l_max = int(max(Lp)+0.5)
//   j(t) = min(floor(t * (total/T)), total-1)  in double (numpy)
//   seg = bsearch(cum, j); loc = j - cum[seg]
//   x = (2*loc+1)/l_max - 1; xs = s*x + tt; p = ((xs+1)*100-1)/2
//   w = (1-frac)*[p0 in 0..99] + frac*[p0 in -1..98]

#define KMAX 256

typedef float f32x4 __attribute__((ext_vector_type(4)));

__global__ __launch_bounds__(256) void fused_kernel(const float* __restrict__ A,
                                                    const float* __restrict__ L,
                                                    float* __restrict__ out,
                                                    int K, int C, int T) {
    __shared__ float  s_s[KMAX];
    __shared__ float  s_t[KMAX];
    __shared__ int    s_cum[KMAX + 1];
    __shared__ int    s_seg[256];
    __shared__ float  s_w[256];
    __shared__ double sd[4];
    __shared__ float  sf[4];
    __shared__ int    si[4];

    const int tid  = threadIdx.x;
    const int lane = tid & 63;
    const int wid  = tid >> 6;

    const float Lv = (tid < K) ? L[tid] : -INFINITY;

    // ---- max(L): wave shfl-reduce, then 4 wave partials ----
    float m = Lv;
    #pragma unroll
    for (int o = 32; o > 0; o >>= 1) m = fmaxf(m, __shfl_xor(m, o));
    if (lane == 0) sf[wid] = m;
    __syncthreads();
    const float maxL = fmaxf(fmaxf(sf[0], sf[1]), fmaxf(sf[2], sf[3]));

    // ---- sum(exp(L-max)) in double ----
    const double e = (tid < K) ? exp((double)Lv - (double)maxL) : 0.0;
    double se = e;
    #pragma unroll
    for (int o = 32; o > 0; o >>= 1) se += __shfl_xor(se, o);
    if (lane == 0) sd[wid] = se;
    __syncthreads();
    const double S = sd[0] + sd[1] + sd[2] + sd[3];

    // Lp as f32 (mirrors jax f32 softmax result)
    const float Lp = (tid < K) ? (float)((double)T * e / S) : 0.0f;

    // ---- l_max = int(max(Lp) + 0.5) ----
    float mp = (tid < K) ? Lp : 0.0f;
    #pragma unroll
    for (int o = 32; o > 0; o >>= 1) mp = fmaxf(mp, __shfl_xor(mp, o));
    __syncthreads();              // everyone done reading phase-1 sf
    if (lane == 0) sf[wid] = mp;
    __syncthreads();
    const int l_max = (int)((double)fmaxf(fmaxf(sf[0], sf[1]), fmaxf(sf[2], sf[3])) + 0.5);

    // ---- r = max(rint(Lp),0); inclusive scan -> cum ----
    int r = 0;
    if (tid < K) {
        r = (int)rintf(Lp);
        if (r < 0) r = 0;
    }
    int v = r;
    #pragma unroll
    for (int o = 1; o < 64; o <<= 1) {
        const int n = __shfl_up(v, o);
        if (lane >= o) v += n;
    }
    if (lane == 63) si[wid] = v;
    __syncthreads();
    int offset = 0;
    for (int w = 0; w < wid; ++w) offset += si[w];
    const int total = si[0] + si[1] + si[2] + si[3];
    if (tid == 0) s_cum[0] = 0;
    if (tid < K) {
        s_cum[tid + 1] = v + offset;
        const float fl = (float)l_max;
        s_s[tid] = fl / Lp;
        s_t[tid] = (fl - Lp) / Lp;
    }
    __syncthreads();

    // ---- per-column: slot j, segment, local offset, edge weight ----
    const int t0 = blockIdx.x * 256;
    {
        const int t = t0 + tid;
        int   seg = 0;
        float w   = 0.0f;
        if (t < T) {
            const double ratio = (double)total / (double)T;
            int j = (int)floor((double)t * ratio);
            if (j > total - 1) j = total - 1;
            if (j < 0) j = 0;

            int lo = 0, hi = K - 1;
            while (lo < hi) {
                const int mid = (lo + hi) >> 1;
                if (s_cum[mid + 1] > j) hi = mid; else lo = mid + 1;
            }
            seg = lo;
            const int loc = j - s_cum[seg];

            const float x  = (2.0f * (float)loc + 1.0f) / (float)l_max - 1.0f;
            const float xs = s_s[seg] * x + s_t[seg];
            const float p  = ((xs + 1.0f) * 100.0f - 1.0f) * 0.5f;
            const float p0 = floorf(p);
            const float w1 = p - p0;
            if (p0 >= 0.0f && p0 <= 99.0f)  w += 1.0f - w1;
            if (p0 >= -1.0f && p0 <= 98.0f) w += w1;
        }
        s_seg[tid] = seg;
        s_w[tid]   = w;
    }
    __syncthreads();

    // ---- stream the 256-col x C tile: float4 along t, 4 channel-rows/pass ----
    const int q  = tid & 63;
    const int cs = tid >> 6;
    const int tq = t0 + q * 4;

    const int   s0 = s_seg[q * 4 + 0], s1 = s_seg[q * 4 + 1];
    const int   s2 = s_seg[q * 4 + 2], s3 = s_seg[q * 4 + 3];
    const float w0 = s_w[q * 4 + 0],   w1 = s_w[q * 4 + 1];
    const float w2 = s_w[q * 4 + 2],   w3 = s_w[q * 4 + 3];

    if (tq + 3 < T) {
        #pragma unroll 4
        for (int cb = 0; cb < C; cb += 4) {
            const int c = cb + cs;
            const float* __restrict__ Ar = A + (size_t)c * K;
            f32x4 vv;
            vv.x = Ar[s0] * w0;
            vv.y = Ar[s1] * w1;
            vv.z = Ar[s2] * w2;
            vv.w = Ar[s3] * w3;
            __builtin_nontemporal_store(vv, (f32x4*)(out + (size_t)c * T + tq));
        }
    } else {
        const int   segs[4] = {s0, s1, s2, s3};
        const float ws[4]   = {w0, w1, w2, w3};
        for (int cb = 0; cb < C; cb += 4) {
            const int c = cb + cs;
            const float* __restrict__ Ar = A + (size_t)c * K;
            for (int u = 0; u < 4; ++u) {
                const int t = tq + u;
                if (t < T) out[(size_t)c * T + t] = Ar[segs[u]] * ws[u];
            }
        }
    }
}

extern "C" void kernel_launch(void* const* d_in, const int* in_sizes, int n_in,
                              void* d_out, int out_size, void* d_ws, size_t ws_size,
                              hipStream_t stream) {
    const float* A = (const float*)d_in[0];
    const float* L = (const float*)d_in[1];

    const int K = in_sizes[1];                 // 256
    const int C = in_sizes[0] / K;             // 256
    const int T = out_size / C;                // 131072

    const int nblk = (T + 255) / 256;
    fused_kernel<<<nblk, 256, 0, stream>>>(A, L, (float*)d_out, K, C, T);
}